// Round 1
// baseline (109.071 us; speedup 1.0000x reference)
//
#include <hip/hip_runtime.h>
#include <math.h>

#define NN 1024
#define PD 16

__device__ __forceinline__ float gelu_tanh(float x) {
    float x3 = x * x * x;
    float inner = 0.7978845608028654f * (x + 0.044715f * x3);
    return 0.5f * x * (1.0f + tanhf(inner));
}

// padded float2 index: +1 float2 per 16 to break power-of-2 bank strides
#define PADI(i) ((i) + ((i) >> 4))

// compiler-only fence: wave-synchronous LDS comm (DS pipe in-order per wave,
// 64 lanes lockstep) — verified correct on this HW in R2/R3.
#define WAVE_FENCE() asm volatile("" ::: "memory")

__device__ __forceinline__ void bf_dif(float2* A, const float2* tw, int i0, int i1, int ti) {
    float2 a = A[PADI(i0)];
    float2 b = A[PADI(i1)];
    float2 c = tw[ti];
    float dx = a.x - b.x, dy = a.y - b.y;
    A[PADI(i0)] = make_float2(a.x + b.x, a.y + b.y);
    A[PADI(i1)] = make_float2(dx * c.x - dy * c.y, dx * c.y + dy * c.x);
}

__device__ __forceinline__ void bf_dit(float2* A, const float2* tw, int i0, int i1, int ti) {
    float2 a = A[PADI(i0)];
    float2 b = A[PADI(i1)];
    float2 c = tw[ti];  // conj applied in-formula
    float tx = b.x * c.x + b.y * c.y;
    float ty = b.y * c.x - b.x * c.y;
    A[PADI(i0)] = make_float2(a.x + tx, a.y + ty);
    A[PADI(i1)] = make_float2(a.x - tx, a.y - ty);
}

// dual-array inverse DIT: wave-local stages 1..8 (fence only), then cross 9,10.
__device__ __forceinline__ void dit_wave_dual(float2* A0, float2* A1, const float2* tw,
                                              int lane, int cb) {
#pragma unroll
    for (int s = 1; s <= 8; ++s) {
        int m = 1 << s, half = m >> 1;
#pragma unroll
        for (int k = 0; k < 2; ++k) {
            int lb = lane + k * 64;
            int grp = lb >> (s - 1), pos = lb & (half - 1);
            int i0 = cb + grp * m + pos;
            int ti = pos << (10 - s);
            bf_dit(A0, tw, i0, i0 + half, ti);
            bf_dit(A1, tw, i0, i0 + half, ti);
        }
        WAVE_FENCE();
    }
}

__device__ __forceinline__ void dit_cross_dual(float2* A0, float2* A1, const float2* tw, int tid) {
    __syncthreads();
#pragma unroll
    for (int k = 0; k < 2; ++k) {
        int w = tid + k * 256;
        int pos = w & 255, i0 = (w >> 8) * 512 + pos;
        bf_dit(A0, tw, i0, i0 + 256, pos << 1);
        bf_dit(A1, tw, i0, i0 + 256, pos << 1);
    }
    __syncthreads();
#pragma unroll
    for (int k = 0; k < 2; ++k) {
        int w = tid + k * 256;
        bf_dit(A0, tw, w, w + 512, w);
        bf_dit(A1, tw, w, w + 512, w);
    }
    __syncthreads();
}

// ---------------- k_main: 256 blocks, 2 rows each via real-packing.
// Z = FFT(h_a + i h_b) (1 fwd FFT). Unpack alpha_a/alpha_b per bin; build
// specA = alpha_a*(m1 + i*m2), specB likewise (m1=1/lam, m2=1/lam^2); two
// packed inverse FFTs give u1+i*u2 for each row. 3 FFTs per 2 rows (was 6).
__global__ __launch_bounds__(256) void k_main(const float* __restrict__ x,
                                              const float* __restrict__ W0,
                                              const float* __restrict__ b0,
                                              float* __restrict__ u1, float* __restrict__ u2,
                                              float* __restrict__ alpha0,
                                              float* __restrict__ A1v, float* __restrict__ A2v) {
    __shared__ float2 A[NN + (NN >> 4)];  // padded work (row a spec / packed u)
    __shared__ float2 B[NN + (NN >> 4)];  // padded work (row b)
    __shared__ float2 Z[NN];              // fwd spectrum, bitrev slots
    __shared__ float2 tw[512];            // e^{-2pi i j/N}
    int blk = blockIdx.x;                 // 0..255
    int bi0 = blk * 2, bi1 = bi0 + 1;
    int b = bi0 >> 6;
    int ia = bi0 & 63, ib = ia + 1;
    int tid = threadIdx.x;
    int lane = tid & 63, wv = tid >> 6, cb = wv << 8;
    int n0 = tid * 4;

    float w00a = W0[ia], w01a = W0[64 + ia], b0a = b0[ia];
    float w00b = W0[ib], w01b = W0[64 + ib], b0b = b0[ib];
    {
        const float4* x0v = (const float4*)(x + b * 2048);
        const float4* x1v = (const float4*)(x + b * 2048 + 1024);
        float4 v0 = x0v[tid];
        float4 v1 = x1v[tid];
        float xe[4] = {v0.x, v0.y, v0.z, v0.w};
        float xo[4] = {v1.x, v1.y, v1.z, v1.w};
#pragma unroll
        for (int j = 0; j < 4; ++j) {
            float hA = xe[j] * w00a + xo[j] * w01a + b0a;
            float hB = xe[j] * w00b + xo[j] * w01b + b0b;
            A[PADI(n0 + j)] = make_float2(hA, hB);  // packed: h_a + i h_b
        }
    }
    for (int j = tid; j < 512; j += 256) {
        float sn, cs;
        sincosf(-6.283185307179586f * (float)j * (1.0f / 1024.0f), &sn, &cs);
        tw[j] = make_float2(cs, sn);
    }
    __syncthreads();  // B1

    // ---- forward DIF (single array): s=10, s=9 cross; s=8..1 wave-local
#pragma unroll
    for (int k = 0; k < 2; ++k) {
        int w = tid + k * 256;
        bf_dif(A, tw, w, w + 512, w);
    }
    __syncthreads();  // B2
#pragma unroll
    for (int k = 0; k < 2; ++k) {
        int w = tid + k * 256;
        int pos = w & 255, i0 = (w >> 8) * 512 + pos;
        bf_dif(A, tw, i0, i0 + 256, pos << 1);
    }
    __syncthreads();  // B3
#pragma unroll
    for (int s = 8; s >= 1; --s) {
        int m = 1 << s, half = m >> 1;
#pragma unroll
        for (int k = 0; k < 2; ++k) {
            int lb = lane + k * 64;
            int grp = lb >> (s - 1), pos = lb & (half - 1);
            int i0 = cb + grp * m + pos;
            bf_dif(A, tw, i0, i0 + half, pos << (10 - s));
        }
        WAVE_FENCE();
    }

    // save Z (wave-local slots), then barrier so cross-wave gathers are safe
#pragma unroll
    for (int j = 0; j < 4; ++j) {
        int r = n0 + j;
        Z[r] = A[PADI(r)];
    }
    if (tid == 0) {
        alpha0[bi0] = Z[0].x;  // alpha_a(0)
        alpha0[bi1] = Z[0].y;  // alpha_b(0)
    }
    __syncthreads();  // B4

    // ---- unpack + combined spectral multiply, thread-local slots
    // alpha_a(k) = (Z(k)+conj(Z(N-k)))/2 ; alpha_b(k) = -i(Z(k)-conj(Z(N-k)))/2
    // M(j) = m1 + i*m2 = -i*(1/w + 1/w^2),  w = 2*pi*f  (f signed)
    // spec = alpha*M = (alpha.y*q, -alpha.x*q), q = 1/w + 1/w^2
#pragma unroll
    for (int j = 0; j < 4; ++j) {
        int r = n0 + j;
        int fj = (int)(__brev((unsigned)r) >> 22);
        if (fj == 0) {
            A[PADI(r)] = make_float2(0.f, 0.f);
            B[PADI(r)] = make_float2(0.f, 0.f);
        } else {
            int jm = (NN - fj) & (NN - 1);
            int rm = (int)(__brev((unsigned)jm) >> 22);
            float2 Zk = Z[r];
            float2 Zm = Z[rm];
            float Cc = Zm.x, Dd = -Zm.y;  // conj(Z(N-k))
            float aax = 0.5f * (Zk.x + Cc), aay = 0.5f * (Zk.y + Dd);
            float abx = 0.5f * (Zk.y - Dd), aby = -0.5f * (Zk.x - Cc);
            float f = (fj < 512) ? (float)fj : (float)(fj - 1024);
            float w = 6.283185307179586f * f;
            float q = 1.0f / w + 1.0f / (w * w);
            A[PADI(r)] = make_float2(aay * q, -aax * q);
            B[PADI(r)] = make_float2(aby * q, -abx * q);
        }
    }
    WAVE_FENCE();

    // ---- dual packed inverse FFT
    dit_wave_dual(A, B, tw, lane, cb);
    dit_cross_dual(A, B, tw, tid);  // trailing barrier

    // ---- outputs: Re -> u1, Im -> u2 for each row
    const float invN = 1.0f / (float)NN;
    {
        float2 a0 = A[PADI(n0 + 0)], a1 = A[PADI(n0 + 1)];
        float2 a2 = A[PADI(n0 + 2)], a3 = A[PADI(n0 + 3)];
        float2 bb0 = B[PADI(n0 + 0)], bb1 = B[PADI(n0 + 1)];
        float2 bb2 = B[PADI(n0 + 2)], bb3 = B[PADI(n0 + 3)];
        ((float4*)(u1 + bi0 * NN))[tid] =
            make_float4(a0.x * invN, a1.x * invN, a2.x * invN, a3.x * invN);
        ((float4*)(u2 + bi0 * NN))[tid] =
            make_float4(a0.y * invN, a1.y * invN, a2.y * invN, a3.y * invN);
        ((float4*)(u1 + bi1 * NN))[tid] =
            make_float4(bb0.x * invN, bb1.x * invN, bb2.x * invN, bb3.x * invN);
        ((float4*)(u2 + bi1 * NN))[tid] =
            make_float4(bb0.y * invN, bb1.y * invN, bb2.y * invN, bb3.y * invN);
        if (tid == 0) {
            A1v[bi0] = a0.x;   // N * u1_a[0]
            A2v[bi0] = a0.y;   // N * u2_a[0]
            A1v[bi1] = bb0.x;
            A2v[bi1] = bb0.y;
        }
    }
}

// ---------------- k_small: fused prep (WA/WB) + coef (c0,c1,c2). 64 blocks x 256.
__global__ __launch_bounds__(256) void k_small(const float* __restrict__ wp,
                                               const float* __restrict__ wpi,
                                               const float* __restrict__ wr,
                                               const float* __restrict__ wri,
                                               const float* __restrict__ alpha0,
                                               const float* __restrict__ A1v,
                                               const float* __restrict__ A2v,
                                               float* __restrict__ WA, float* __restrict__ WB,
                                               float* __restrict__ c0, float* __restrict__ c1,
                                               float* __restrict__ c2) {
    __shared__ float a0s[512], a1s[512], a2s[512];
    __shared__ float wred[4][16][28];  // [wave][p][quantity]
    int o = blockIdx.x;
    int tid = threadIdx.x;
    int p = tid & 15;
    int i4 = tid >> 4;
    for (int t = tid; t < 512; t += 256) {
        a0s[t] = alpha0[t];
        a1s[t] = A1v[t];
        a2s[t] = A2v[t];
    }
    __syncthreads();

    float p1x = 0.f, p1y = 0.f, p2x = 0.f, p2y = 0.f;
    float r2x[8], r2y[8], t0[8];
#pragma unroll
    for (int b = 0; b < 8; ++b) { r2x[b] = 0.f; r2y[b] = 0.f; t0[b] = 0.f; }
    float rrs[4], rpxs[4];

#pragma unroll
    for (int ibl = 0; ibl < 4; ++ibl) {
        int i = ibl * 16 + i4;
        int idx = (i * 64 + o) * PD + p;
        float rr = wr[idx], ri = wri[idx], pr = wp[idx], pim = wpi[idx];
        float inv = 1.0f / (pr * pr + pim * pim);
        float ripx = (rr * pr + ri * pim) * inv;  // Re(res/pole)
        float ripy = (ri * pr - rr * pim) * inv;  // Im(res/pole)
        float rpx = rr * pr - ri * pim;           // Re(res*pole)
        float rpy = rr * pim + ri * pr;           // Im(res*pole)
        rrs[ibl] = rr;
        rpxs[ibl] = rpx;
        p1x += pr; p1y += pim;
        p2x += pr * pr - pim * pim;
        p2y += 2.0f * pr * pim;
#pragma unroll
        for (int b = 0; b < 8; ++b) {
            float a1 = a1s[b * 64 + i], a2 = a2s[b * 64 + i], a0 = a0s[b * 64 + i];
            r2x[b] += -rr * a1 - rpx * a2 + ripx * a0;
            r2y[b] += -ri * a1 - rpy * a2 + ripy * a0;
            t0[b] += -a0 * ripx;
        }
    }

#pragma unroll
    for (int ibl = 0; ibl < 4; ++ibl) {
        float wa = rrs[ibl], wb = rpxs[ibl];
        for (int off = 8; off >= 1; off >>= 1) {
            wa += __shfl_xor(wa, off);
            wb += __shfl_xor(wb, off);
        }
        if (p == 0) {
            int i = ibl * 16 + i4;
            WA[i * 64 + o] = wa;
            WB[i * 64 + o] = wb;
        }
    }

    float q[28];
    q[0] = p1x; q[1] = p1y; q[2] = p2x; q[3] = p2y;
#pragma unroll
    for (int b = 0; b < 8; ++b) { q[4 + b] = r2x[b]; q[12 + b] = r2y[b]; q[20 + b] = t0[b]; }
#pragma unroll
    for (int k = 0; k < 28; ++k) {
        q[k] += __shfl_down(q[k], 32);
        q[k] += __shfl_down(q[k], 16);
    }
    int lane = tid & 63, wv = tid >> 6;
    if (lane < 16) {
#pragma unroll
        for (int k = 0; k < 28; ++k) wred[wv][lane][k] = q[k];
    }
    __syncthreads();
    if (tid < 16) {
        float s[28];
#pragma unroll
        for (int k = 0; k < 28; ++k)
            s[k] = wred[0][tid][k] + wred[1][tid][k] + wred[2][tid][k] + wred[3][tid][k];
        const float invN = 1.0f / 1024.0f;
        float cc[24];
#pragma unroll
        for (int b = 0; b < 8; ++b) {
            float rx = s[4 + b], ry = s[12 + b];
            cc[b] = (64.0f * rx + s[20 + b]) * invN;
            cc[8 + b] = (rx * s[0] - ry * s[1]) * invN;
            cc[16 + b] = (rx * s[2] - ry * s[3]) * (0.5f * invN);
        }
#pragma unroll
        for (int k = 0; k < 24; ++k) {
            cc[k] += __shfl_xor(cc[k], 1);
            cc[k] += __shfl_xor(cc[k], 2);
            cc[k] += __shfl_xor(cc[k], 4);
            cc[k] += __shfl_xor(cc[k], 8);
        }
        if (tid == 0) {
#pragma unroll
            for (int b = 0; b < 8; ++b) {
                c0[b * 64 + o] = cc[b];
                c1[b * 64 + o] = cc[8 + b];
                c2[b * 64 + o] = cc[16 + b];
            }
        }
    }
}

// ---------------- k_gout: fused g + out. 512 blocks x 256 threads.
// R0 restructure: 16 cols/block (was 32) -> 512 blocks so 2 blocks/CU can
// co-reside; LDS cut to ~64 KB by reusing sWl's buffer for W1 in Phase B.
// Theory: latency-bound at 1 blk/CU (VALUBusy 12.8%, occ 8.9%); 2 waves/SIMD
// should ~halve exposed LDS/VALU dependency latency.
__global__ __launch_bounds__(256) void k_gout(const float* __restrict__ x,
                                              const float* __restrict__ W0,
                                              const float* __restrict__ b0,
                                              const float* __restrict__ u1,
                                              const float* __restrict__ u2,
                                              const float* __restrict__ WA,
                                              const float* __restrict__ WB,
                                              const float* __restrict__ Wl,
                                              const float* __restrict__ bl,
                                              const float* __restrict__ c0,
                                              const float* __restrict__ c1,
                                              const float* __restrict__ c2,
                                              const float* __restrict__ W1,
                                              const float* __restrict__ b1,
                                              const float* __restrict__ W2,
                                              const float* __restrict__ b2,
                                              float* __restrict__ out) {
    __shared__ float sU1[64 * 16], sU2[64 * 16];          // [i][n] 4 KB each
    __shared__ float sWl[4096], sWA[4096], sWB[4096];     // [i][o]; sWl reused for W1 [o][k]
    __shared__ float hhs[64 * 18];                        // [o][n] pad->18 (2-way max)
    __shared__ float sW0a[64], sW0b[64], sb0[64], sbl[64];
    __shared__ float sc0[64], sc1[64], sc2[64], sb1[64], sW2[64];
    __shared__ float red[16 * 16];
    int tid = threadIdx.x;
    int b = blockIdx.x >> 6;          // 0..7
    int n0 = (blockIdx.x & 63) << 4;  // 16-col tile

    {
        const float4* Wl4 = (const float4*)Wl;
        const float4* WA4 = (const float4*)WA;
        const float4* WB4 = (const float4*)WB;
        for (int j = tid; j < 1024; j += 256) {
            ((float4*)sWl)[j] = Wl4[j];
            ((float4*)sWA)[j] = WA4[j];
            ((float4*)sWB)[j] = WB4[j];
        }
        const float4* u14 = (const float4*)u1;
        const float4* u24 = (const float4*)u2;
        int nb4 = n0 >> 2;
        {
            int i = tid >> 2, c4 = tid & 3;  // 256 threads = 64 rows x 4 float4
            ((float4*)sU1)[tid] = u14[(b * 64 + i) * 256 + nb4 + c4];
            ((float4*)sU2)[tid] = u24[(b * 64 + i) * 256 + nb4 + c4];
        }
        if (tid < 64) {
            sW0a[tid] = W0[tid];
            sW0b[tid] = W0[64 + tid];
            sb0[tid] = b0[tid];
            sbl[tid] = bl[tid];
            sc0[tid] = c0[b * 64 + tid];
            sc1[tid] = c1[b * 64 + tid];
            sc2[tid] = c2[b * 64 + tid];
            sb1[tid] = b1[tid];
            sW2[tid] = W2[tid];
        }
    }
    __syncthreads();

    // Phase A: og = tid>>4 (16 groups x 4 o), ng = tid&15 (1 col each)
    {
        int og = tid >> 4, ng = tid & 15;
        int oB = og * 4;
        float x0 = x[b * 2048 + n0 + ng];
        float x1 = x[b * 2048 + 1024 + n0 + ng];
        float acc0 = 0.f, acc1 = 0.f, acc2 = 0.f, acc3 = 0.f;
        for (int i = 0; i < 64; ++i) {
            float hv = x0 * sW0a[i] + x1 * sW0b[i] + sb0[i];
            float uv = sU1[i * 16 + ng];
            float vv = sU2[i * 16 + ng];
            float4 wl = *(const float4*)&sWl[i * 64 + oB];
            float4 wa = *(const float4*)&sWA[i * 64 + oB];
            float4 wb = *(const float4*)&sWB[i * 64 + oB];
            acc0 += hv * wl.x + uv * wa.x + vv * wb.x;
            acc1 += hv * wl.y + uv * wa.y + vv * wb.y;
            acc2 += hv * wl.z + uv * wa.z + vv * wb.z;
            acc3 += hv * wl.w + uv * wa.w + vv * wb.w;
        }
        float ta = (float)(n0 + ng) * (1.0f / 1023.0f);
        float ta2 = ta * ta;
        float accs[4] = {acc0, acc1, acc2, acc3};
#pragma unroll
        for (int r = 0; r < 4; ++r) {
            int o = oB + r;
            float ga = accs[r] + sbl[o] + sc0[o] + sc1[o] * ta + sc2[o] * ta2;
            hhs[o * 18 + ng] = gelu_tanh(ga);
        }
    }
    __syncthreads();

    // reload W1 into sWl's buffer (Phase A done with Wl)
    {
        const float4* W14 = (const float4*)W1;
        for (int j = tid; j < 1024; j += 256) ((float4*)sWl)[j] = W14[j];
    }
    __syncthreads();

    // Phase B: n = tid&15, kq = tid>>4 (16 groups x 4 k)
    {
        int n = tid & 15, kq = tid >> 4;
        float z0 = 0.f, z1 = 0.f, z2 = 0.f, z3 = 0.f;
        for (int o = 0; o < 64; ++o) {
            float hv = hhs[o * 18 + n];
            float4 w1 = *(const float4*)&sWl[o * 64 + kq * 4];
            z0 += hv * w1.x;
            z1 += hv * w1.y;
            z2 += hv * w1.z;
            z3 += hv * w1.w;
        }
        float part = gelu_tanh(z0 + sb1[kq * 4 + 0]) * sW2[kq * 4 + 0] +
                     gelu_tanh(z1 + sb1[kq * 4 + 1]) * sW2[kq * 4 + 1] +
                     gelu_tanh(z2 + sb1[kq * 4 + 2]) * sW2[kq * 4 + 2] +
                     gelu_tanh(z3 + sb1[kq * 4 + 3]) * sW2[kq * 4 + 3];
        red[kq * 16 + n] = part;
    }
    __syncthreads();
    if (tid < 16) {
        float s = red[tid];
#pragma unroll
        for (int k = 1; k < 16; ++k) s += red[k * 16 + tid];
        out[b * 1024 + n0 + tid] = s + b2[0];
    }
}

extern "C" void kernel_launch(void* const* d_in, const int* in_sizes, int n_in,
                              void* d_out, int out_size, void* d_ws, size_t ws_size,
                              hipStream_t stream) {
    const float* x = (const float*)d_in[0];
    const float* W0 = (const float*)d_in[1];
    const float* b0 = (const float*)d_in[2];
    const float* wp = (const float*)d_in[3];
    const float* wpi = (const float*)d_in[4];
    const float* wr = (const float*)d_in[5];
    const float* wri = (const float*)d_in[6];
    const float* Wl = (const float*)d_in[7];
    const float* bl = (const float*)d_in[8];
    const float* W1 = (const float*)d_in[9];
    const float* b1 = (const float*)d_in[10];
    const float* W2 = (const float*)d_in[11];
    const float* b2 = (const float*)d_in[12];

    float* ws = (float*)d_ws;
    float* u1 = ws;                    // 524288
    float* u2 = ws + 524288;           // 524288
    float* alpha0 = ws + 1048576;      // 512
    float* A1v = alpha0 + 512;
    float* A2v = alpha0 + 1024;
    float* c0 = alpha0 + 1536;
    float* c1 = alpha0 + 2048;
    float* c2 = alpha0 + 2560;
    float* WA = alpha0 + 3072;         // 4096
    float* WB = alpha0 + 3072 + 4096;  // 4096

    k_main<<<256, 256, 0, stream>>>(x, W0, b0, u1, u2, alpha0, A1v, A2v);
    k_small<<<64, 256, 0, stream>>>(wp, wpi, wr, wri, alpha0, A1v, A2v, WA, WB, c0, c1, c2);
    k_gout<<<512, 256, 0, stream>>>(x, W0, b0, u1, u2, WA, WB, Wl, bl, c0, c1, c2,
                                    W1, b1, W2, b2, (float*)d_out);
}

// Round 2
// 106.074 us; speedup vs baseline: 1.0282x; 1.0282x over previous
//
#include <hip/hip_runtime.h>
#include <math.h>

#define NN 1024
#define PD 16

__device__ __forceinline__ float gelu_tanh(float x) {
    float x3 = x * x * x;
    float inner = 0.7978845608028654f * (x + 0.044715f * x3);
    return 0.5f * x * (1.0f + tanhf(inner));
}

// padded float2 index: +1 float2 per 16 to break power-of-2 bank strides
#define PADI(i) ((i) + ((i) >> 4))

// compiler-only fence: wave-synchronous LDS comm (DS pipe in-order per wave,
// 64 lanes lockstep) — verified correct on this HW in R2/R3.
#define WAVE_FENCE() asm volatile("" ::: "memory")

__device__ __forceinline__ void bf_dif(float2* A, const float2* tw, int i0, int i1, int ti) {
    float2 a = A[PADI(i0)];
    float2 b = A[PADI(i1)];
    float2 c = tw[ti];
    float dx = a.x - b.x, dy = a.y - b.y;
    A[PADI(i0)] = make_float2(a.x + b.x, a.y + b.y);
    A[PADI(i1)] = make_float2(dx * c.x - dy * c.y, dx * c.y + dy * c.x);
}

__device__ __forceinline__ void bf_dit(float2* A, const float2* tw, int i0, int i1, int ti) {
    float2 a = A[PADI(i0)];
    float2 b = A[PADI(i1)];
    float2 c = tw[ti];  // conj applied in-formula
    float tx = b.x * c.x + b.y * c.y;
    float ty = b.y * c.x - b.x * c.y;
    A[PADI(i0)] = make_float2(a.x + tx, a.y + ty);
    A[PADI(i1)] = make_float2(a.x - tx, a.y - ty);
}

// dual-array inverse DIT: wave-local stages 1..8 (fence only), then cross 9,10.
__device__ __forceinline__ void dit_wave_dual(float2* A0, float2* A1, const float2* tw,
                                              int lane, int cb) {
#pragma unroll
    for (int s = 1; s <= 8; ++s) {
        int m = 1 << s, half = m >> 1;
#pragma unroll
        for (int k = 0; k < 2; ++k) {
            int lb = lane + k * 64;
            int grp = lb >> (s - 1), pos = lb & (half - 1);
            int i0 = cb + grp * m + pos;
            int ti = pos << (10 - s);
            bf_dit(A0, tw, i0, i0 + half, ti);
            bf_dit(A1, tw, i0, i0 + half, ti);
        }
        WAVE_FENCE();
    }
}

__device__ __forceinline__ void dit_cross_dual(float2* A0, float2* A1, const float2* tw, int tid) {
    __syncthreads();
#pragma unroll
    for (int k = 0; k < 2; ++k) {
        int w = tid + k * 256;
        int pos = w & 255, i0 = (w >> 8) * 512 + pos;
        bf_dit(A0, tw, i0, i0 + 256, pos << 1);
        bf_dit(A1, tw, i0, i0 + 256, pos << 1);
    }
    __syncthreads();
#pragma unroll
    for (int k = 0; k < 2; ++k) {
        int w = tid + k * 256;
        bf_dit(A0, tw, w, w + 512, w);
        bf_dit(A1, tw, w, w + 512, w);
    }
    __syncthreads();
}

// ---------------- k_main: 256 blocks, 2 rows each via real-packing.
__global__ __launch_bounds__(256) void k_main(const float* __restrict__ x,
                                              const float* __restrict__ W0,
                                              const float* __restrict__ b0,
                                              float* __restrict__ u1, float* __restrict__ u2,
                                              float* __restrict__ alpha0,
                                              float* __restrict__ A1v, float* __restrict__ A2v) {
    __shared__ float2 A[NN + (NN >> 4)];  // padded work (row a spec / packed u)
    __shared__ float2 B[NN + (NN >> 4)];  // padded work (row b)
    __shared__ float2 Z[NN];              // fwd spectrum, bitrev slots
    __shared__ float2 tw[512];            // e^{-2pi i j/N}
    int blk = blockIdx.x;                 // 0..255
    int bi0 = blk * 2, bi1 = bi0 + 1;
    int b = bi0 >> 6;
    int ia = bi0 & 63, ib = ia + 1;
    int tid = threadIdx.x;
    int lane = tid & 63, wv = tid >> 6, cb = wv << 8;
    int n0 = tid * 4;

    float w00a = W0[ia], w01a = W0[64 + ia], b0a = b0[ia];
    float w00b = W0[ib], w01b = W0[64 + ib], b0b = b0[ib];
    {
        const float4* x0v = (const float4*)(x + b * 2048);
        const float4* x1v = (const float4*)(x + b * 2048 + 1024);
        float4 v0 = x0v[tid];
        float4 v1 = x1v[tid];
        float xe[4] = {v0.x, v0.y, v0.z, v0.w};
        float xo[4] = {v1.x, v1.y, v1.z, v1.w};
#pragma unroll
        for (int j = 0; j < 4; ++j) {
            float hA = xe[j] * w00a + xo[j] * w01a + b0a;
            float hB = xe[j] * w00b + xo[j] * w01b + b0b;
            A[PADI(n0 + j)] = make_float2(hA, hB);  // packed: h_a + i h_b
        }
    }
    for (int j = tid; j < 512; j += 256) {
        float sn, cs;
        sincosf(-6.283185307179586f * (float)j * (1.0f / 1024.0f), &sn, &cs);
        tw[j] = make_float2(cs, sn);
    }
    __syncthreads();  // B1

    // ---- forward DIF (single array): s=10, s=9 cross; s=8..1 wave-local
#pragma unroll
    for (int k = 0; k < 2; ++k) {
        int w = tid + k * 256;
        bf_dif(A, tw, w, w + 512, w);
    }
    __syncthreads();  // B2
#pragma unroll
    for (int k = 0; k < 2; ++k) {
        int w = tid + k * 256;
        int pos = w & 255, i0 = (w >> 8) * 512 + pos;
        bf_dif(A, tw, i0, i0 + 256, pos << 1);
    }
    __syncthreads();  // B3
#pragma unroll
    for (int s = 8; s >= 1; --s) {
        int m = 1 << s, half = m >> 1;
#pragma unroll
        for (int k = 0; k < 2; ++k) {
            int lb = lane + k * 64;
            int grp = lb >> (s - 1), pos = lb & (half - 1);
            int i0 = cb + grp * m + pos;
            bf_dif(A, tw, i0, i0 + half, pos << (10 - s));
        }
        WAVE_FENCE();
    }

    // save Z (wave-local slots), then barrier so cross-wave gathers are safe
#pragma unroll
    for (int j = 0; j < 4; ++j) {
        int r = n0 + j;
        Z[r] = A[PADI(r)];
    }
    if (tid == 0) {
        alpha0[bi0] = Z[0].x;  // alpha_a(0)
        alpha0[bi1] = Z[0].y;  // alpha_b(0)
    }
    __syncthreads();  // B4

    // ---- unpack + combined spectral multiply, thread-local slots
#pragma unroll
    for (int j = 0; j < 4; ++j) {
        int r = n0 + j;
        int fj = (int)(__brev((unsigned)r) >> 22);
        if (fj == 0) {
            A[PADI(r)] = make_float2(0.f, 0.f);
            B[PADI(r)] = make_float2(0.f, 0.f);
        } else {
            int jm = (NN - fj) & (NN - 1);
            int rm = (int)(__brev((unsigned)jm) >> 22);
            float2 Zk = Z[r];
            float2 Zm = Z[rm];
            float Cc = Zm.x, Dd = -Zm.y;  // conj(Z(N-k))
            float aax = 0.5f * (Zk.x + Cc), aay = 0.5f * (Zk.y + Dd);
            float abx = 0.5f * (Zk.y - Dd), aby = -0.5f * (Zk.x - Cc);
            float f = (fj < 512) ? (float)fj : (float)(fj - 1024);
            float w = 6.283185307179586f * f;
            float q = 1.0f / w + 1.0f / (w * w);
            A[PADI(r)] = make_float2(aay * q, -aax * q);
            B[PADI(r)] = make_float2(aby * q, -abx * q);
        }
    }
    WAVE_FENCE();

    // ---- dual packed inverse FFT
    dit_wave_dual(A, B, tw, lane, cb);
    dit_cross_dual(A, B, tw, tid);  // trailing barrier

    // ---- outputs: Re -> u1, Im -> u2 for each row
    const float invN = 1.0f / (float)NN;
    {
        float2 a0 = A[PADI(n0 + 0)], a1 = A[PADI(n0 + 1)];
        float2 a2 = A[PADI(n0 + 2)], a3 = A[PADI(n0 + 3)];
        float2 bb0 = B[PADI(n0 + 0)], bb1 = B[PADI(n0 + 1)];
        float2 bb2 = B[PADI(n0 + 2)], bb3 = B[PADI(n0 + 3)];
        ((float4*)(u1 + bi0 * NN))[tid] =
            make_float4(a0.x * invN, a1.x * invN, a2.x * invN, a3.x * invN);
        ((float4*)(u2 + bi0 * NN))[tid] =
            make_float4(a0.y * invN, a1.y * invN, a2.y * invN, a3.y * invN);
        ((float4*)(u1 + bi1 * NN))[tid] =
            make_float4(bb0.x * invN, bb1.x * invN, bb2.x * invN, bb3.x * invN);
        ((float4*)(u2 + bi1 * NN))[tid] =
            make_float4(bb0.y * invN, bb1.y * invN, bb2.y * invN, bb3.y * invN);
        if (tid == 0) {
            A1v[bi0] = a0.x;   // N * u1_a[0]
            A2v[bi0] = a0.y;   // N * u2_a[0]
            A1v[bi1] = bb0.x;
            A2v[bi1] = bb0.y;
        }
    }
}

// ---------------- k_small: fused prep (WA/WB) + coef (c0,c1,c2). 64 blocks x 256.
__global__ __launch_bounds__(256) void k_small(const float* __restrict__ wp,
                                               const float* __restrict__ wpi,
                                               const float* __restrict__ wr,
                                               const float* __restrict__ wri,
                                               const float* __restrict__ alpha0,
                                               const float* __restrict__ A1v,
                                               const float* __restrict__ A2v,
                                               float* __restrict__ WA, float* __restrict__ WB,
                                               float* __restrict__ c0, float* __restrict__ c1,
                                               float* __restrict__ c2) {
    __shared__ float a0s[512], a1s[512], a2s[512];
    __shared__ float wred[4][16][28];  // [wave][p][quantity]
    int o = blockIdx.x;
    int tid = threadIdx.x;
    int p = tid & 15;
    int i4 = tid >> 4;
    for (int t = tid; t < 512; t += 256) {
        a0s[t] = alpha0[t];
        a1s[t] = A1v[t];
        a2s[t] = A2v[t];
    }
    __syncthreads();

    float p1x = 0.f, p1y = 0.f, p2x = 0.f, p2y = 0.f;
    float r2x[8], r2y[8], t0[8];
#pragma unroll
    for (int b = 0; b < 8; ++b) { r2x[b] = 0.f; r2y[b] = 0.f; t0[b] = 0.f; }
    float rrs[4], rpxs[4];

#pragma unroll
    for (int ibl = 0; ibl < 4; ++ibl) {
        int i = ibl * 16 + i4;
        int idx = (i * 64 + o) * PD + p;
        float rr = wr[idx], ri = wri[idx], pr = wp[idx], pim = wpi[idx];
        float inv = 1.0f / (pr * pr + pim * pim);
        float ripx = (rr * pr + ri * pim) * inv;  // Re(res/pole)
        float ripy = (ri * pr - rr * pim) * inv;  // Im(res/pole)
        float rpx = rr * pr - ri * pim;           // Re(res*pole)
        float rpy = rr * pim + ri * pr;           // Im(res*pole)
        rrs[ibl] = rr;
        rpxs[ibl] = rpx;
        p1x += pr; p1y += pim;
        p2x += pr * pr - pim * pim;
        p2y += 2.0f * pr * pim;
#pragma unroll
        for (int b = 0; b < 8; ++b) {
            float a1 = a1s[b * 64 + i], a2 = a2s[b * 64 + i], a0 = a0s[b * 64 + i];
            r2x[b] += -rr * a1 - rpx * a2 + ripx * a0;
            r2y[b] += -ri * a1 - rpy * a2 + ripy * a0;
            t0[b] += -a0 * ripx;
        }
    }

#pragma unroll
    for (int ibl = 0; ibl < 4; ++ibl) {
        float wa = rrs[ibl], wb = rpxs[ibl];
        for (int off = 8; off >= 1; off >>= 1) {
            wa += __shfl_xor(wa, off);
            wb += __shfl_xor(wb, off);
        }
        if (p == 0) {
            int i = ibl * 16 + i4;
            WA[i * 64 + o] = wa;
            WB[i * 64 + o] = wb;
        }
    }

    float q[28];
    q[0] = p1x; q[1] = p1y; q[2] = p2x; q[3] = p2y;
#pragma unroll
    for (int b = 0; b < 8; ++b) { q[4 + b] = r2x[b]; q[12 + b] = r2y[b]; q[20 + b] = t0[b]; }
#pragma unroll
    for (int k = 0; k < 28; ++k) {
        q[k] += __shfl_down(q[k], 32);
        q[k] += __shfl_down(q[k], 16);
    }
    int lane = tid & 63, wv = tid >> 6;
    if (lane < 16) {
#pragma unroll
        for (int k = 0; k < 28; ++k) wred[wv][lane][k] = q[k];
    }
    __syncthreads();
    if (tid < 16) {
        float s[28];
#pragma unroll
        for (int k = 0; k < 28; ++k)
            s[k] = wred[0][tid][k] + wred[1][tid][k] + wred[2][tid][k] + wred[3][tid][k];
        const float invN = 1.0f / 1024.0f;
        float cc[24];
#pragma unroll
        for (int b = 0; b < 8; ++b) {
            float rx = s[4 + b], ry = s[12 + b];
            cc[b] = (64.0f * rx + s[20 + b]) * invN;
            cc[8 + b] = (rx * s[0] - ry * s[1]) * invN;
            cc[16 + b] = (rx * s[2] - ry * s[3]) * (0.5f * invN);
        }
#pragma unroll
        for (int k = 0; k < 24; ++k) {
            cc[k] += __shfl_xor(cc[k], 1);
            cc[k] += __shfl_xor(cc[k], 2);
            cc[k] += __shfl_xor(cc[k], 4);
            cc[k] += __shfl_xor(cc[k], 8);
        }
        if (tid == 0) {
#pragma unroll
            for (int b = 0; b < 8; ++b) {
                c0[b * 64 + o] = cc[b];
                c1[b * 64 + o] = cc[8 + b];
                c2[b * 64 + o] = cc[16 + b];
            }
        }
    }
}

// ---------------- k_gout v2: register-tiled GEMMs. 256 blocks x 256 threads.
// R1 post-mortem: Phase A was LDS-THROUGHPUT-bound (8 DS instrs per 12 FMA;
// per-CU DS pipe shared -> extra occupancy was useless). Fix: 4x4 register
// tiles so each ds_read_b128 feeds 16 FMAs. h precomputed once into LDS.
// Per-iter: 6 b128 (~72 DS-cy) vs 48 FMA (96 VALU-cy). 128 GEMM threads;
// DS-bound => idle waves are free. All LDS access float4, bank-conflict-free.
__global__ __launch_bounds__(256) void k_gout(const float* __restrict__ x,
                                              const float* __restrict__ W0,
                                              const float* __restrict__ b0,
                                              const float* __restrict__ u1,
                                              const float* __restrict__ u2,
                                              const float* __restrict__ WA,
                                              const float* __restrict__ WB,
                                              const float* __restrict__ Wl,
                                              const float* __restrict__ bl,
                                              const float* __restrict__ c0,
                                              const float* __restrict__ c1,
                                              const float* __restrict__ c2,
                                              const float* __restrict__ W1,
                                              const float* __restrict__ b1,
                                              const float* __restrict__ W2,
                                              const float* __restrict__ b2,
                                              float* __restrict__ out) {
    __shared__ float sWl[4096], sWA[4096], sWB[4096], sW1[4096];  // 64 KB, [i][o]/[o][k]
    __shared__ float sH[2048], sU1s[2048], sU2s[2048];            // [i][32n] 8 KB each
    __shared__ float hhs[2048];                                   // [o][32n]
    __shared__ float sW0a[64], sW0b[64], sb0[64], sbl[64];
    __shared__ float sc0[64], sc1[64], sc2[64], sb1[64], sW2[64];
    __shared__ float sx0[32], sx1[32];
    __shared__ float red[512];  // [16 kg][32 n]
    int tid = threadIdx.x;
    int b = blockIdx.x >> 5;          // 0..7
    int n0 = (blockIdx.x & 31) << 5;  // 32-col tile

    // ---- stage
    {
        const float4* Wl4 = (const float4*)Wl;
        const float4* WA4 = (const float4*)WA;
        const float4* WB4 = (const float4*)WB;
        const float4* W14 = (const float4*)W1;
        for (int j = tid; j < 1024; j += 256) {
            ((float4*)sWl)[j] = Wl4[j];
            ((float4*)sWA)[j] = WA4[j];
            ((float4*)sWB)[j] = WB4[j];
            ((float4*)sW1)[j] = W14[j];
        }
        const float4* u14 = (const float4*)u1;
        const float4* u24 = (const float4*)u2;
        int nb4 = n0 >> 2;
        for (int j = tid; j < 512; j += 256) {
            int i = j >> 3, c4 = j & 7;
            ((float4*)sU1s)[i * 8 + c4] = u14[(b * 64 + i) * 256 + nb4 + c4];
            ((float4*)sU2s)[i * 8 + c4] = u24[(b * 64 + i) * 256 + nb4 + c4];
        }
        if (tid < 64) {
            sW0a[tid] = W0[tid];
            sW0b[tid] = W0[64 + tid];
            sb0[tid] = b0[tid];
            sbl[tid] = bl[tid];
            sc0[tid] = c0[b * 64 + tid];
            sc1[tid] = c1[b * 64 + tid];
            sc2[tid] = c2[b * 64 + tid];
            sb1[tid] = b1[tid];
            sW2[tid] = W2[tid];
        }
        if (tid < 32) {
            sx0[tid] = x[b * 2048 + n0 + tid];
            sx1[tid] = x[b * 2048 + 1024 + n0 + tid];
        }
    }
    __syncthreads();

    // ---- h precompute into sH: 512 float4 slots, 2 per thread (conflict-free)
    {
#pragma unroll
        for (int t = 0; t < 2; ++t) {
            int j = tid + t * 256;
            int i = j >> 3, c4 = (j & 7) * 4;
            float wa_ = sW0a[i], wb_ = sW0b[i], bb = sb0[i];
            float4 hv;
            hv.x = sx0[c4 + 0] * wa_ + sx1[c4 + 0] * wb_ + bb;
            hv.y = sx0[c4 + 1] * wa_ + sx1[c4 + 1] * wb_ + bb;
            hv.z = sx0[c4 + 2] * wa_ + sx1[c4 + 2] * wb_ + bb;
            hv.w = sx0[c4 + 3] * wa_ + sx1[c4 + 3] * wb_ + bb;
            *(float4*)&sH[i * 32 + c4] = hv;
        }
    }
    __syncthreads();

    // ---- Phase A GEMM: 128 threads, 4o x 4n register tile, K=64
    if (tid < 128) {
        int og = tid >> 3, ng = tid & 7;
        int oB = og * 4, nB = ng * 4;
        float acc[4][4];
#pragma unroll
        for (int r = 0; r < 4; ++r)
#pragma unroll
            for (int c = 0; c < 4; ++c) acc[r][c] = 0.f;
        for (int i = 0; i < 64; ++i) {
            float4 wl = *(const float4*)&sWl[i * 64 + oB];
            float4 wa = *(const float4*)&sWA[i * 64 + oB];
            float4 wb = *(const float4*)&sWB[i * 64 + oB];
            float4 h4 = *(const float4*)&sH[i * 32 + nB];
            float4 u4 = *(const float4*)&sU1s[i * 32 + nB];
            float4 v4 = *(const float4*)&sU2s[i * 32 + nB];
            float wlv[4] = {wl.x, wl.y, wl.z, wl.w};
            float wav[4] = {wa.x, wa.y, wa.z, wa.w};
            float wbv[4] = {wb.x, wb.y, wb.z, wb.w};
            float hv[4] = {h4.x, h4.y, h4.z, h4.w};
            float uv[4] = {u4.x, u4.y, u4.z, u4.w};
            float vv[4] = {v4.x, v4.y, v4.z, v4.w};
#pragma unroll
            for (int r = 0; r < 4; ++r)
#pragma unroll
                for (int c = 0; c < 4; ++c)
                    acc[r][c] += wlv[r] * hv[c] + wav[r] * uv[c] + wbv[r] * vv[c];
        }
#pragma unroll
        for (int r = 0; r < 4; ++r) {
            int o = oB + r;
            float base = sbl[o] + sc0[o];
            float s1 = sc1[o], s2 = sc2[o];
            float4 g;
            {
                float t = (float)(n0 + nB + 0) * (1.0f / 1023.0f);
                g.x = gelu_tanh(acc[r][0] + base + s1 * t + s2 * t * t);
            }
            {
                float t = (float)(n0 + nB + 1) * (1.0f / 1023.0f);
                g.y = gelu_tanh(acc[r][1] + base + s1 * t + s2 * t * t);
            }
            {
                float t = (float)(n0 + nB + 2) * (1.0f / 1023.0f);
                g.z = gelu_tanh(acc[r][2] + base + s1 * t + s2 * t * t);
            }
            {
                float t = (float)(n0 + nB + 3) * (1.0f / 1023.0f);
                g.w = gelu_tanh(acc[r][3] + base + s1 * t + s2 * t * t);
            }
            *(float4*)&hhs[o * 32 + nB] = g;
        }
    }
    __syncthreads();

    // ---- Phase B GEMM: 128 threads, 4k x 4n register tile, K=64(o)
    if (tid < 128) {
        int kg = tid >> 3, ng = tid & 7;
        int kB = kg * 4, nB = ng * 4;
        float z[4][4];
#pragma unroll
        for (int r = 0; r < 4; ++r)
#pragma unroll
            for (int c = 0; c < 4; ++c) z[r][c] = 0.f;
        for (int o = 0; o < 64; ++o) {
            float4 w1 = *(const float4*)&sW1[o * 64 + kB];
            float4 h4 = *(const float4*)&hhs[o * 32 + nB];
            float w1v[4] = {w1.x, w1.y, w1.z, w1.w};
            float hv[4] = {h4.x, h4.y, h4.z, h4.w};
#pragma unroll
            for (int r = 0; r < 4; ++r)
#pragma unroll
                for (int c = 0; c < 4; ++c) z[r][c] += w1v[r] * hv[c];
        }
        float part[4];
#pragma unroll
        for (int c = 0; c < 4; ++c) part[c] = 0.f;
#pragma unroll
        for (int r = 0; r < 4; ++r) {
            float bb = sb1[kB + r], w2 = sW2[kB + r];
#pragma unroll
            for (int c = 0; c < 4; ++c) part[c] += gelu_tanh(z[r][c] + bb) * w2;
        }
        *(float4*)&red[kg * 32 + nB] = make_float4(part[0], part[1], part[2], part[3]);
    }
    __syncthreads();

    if (tid < 32) {
        float s = red[tid];
#pragma unroll
        for (int k = 1; k < 16; ++k) s += red[k * 32 + tid];
        out[b * 1024 + n0 + tid] = s + b2[0];
    }
}

extern "C" void kernel_launch(void* const* d_in, const int* in_sizes, int n_in,
                              void* d_out, int out_size, void* d_ws, size_t ws_size,
                              hipStream_t stream) {
    const float* x = (const float*)d_in[0];
    const float* W0 = (const float*)d_in[1];
    const float* b0 = (const float*)d_in[2];
    const float* wp = (const float*)d_in[3];
    const float* wpi = (const float*)d_in[4];
    const float* wr = (const float*)d_in[5];
    const float* wri = (const float*)d_in[6];
    const float* Wl = (const float*)d_in[7];
    const float* bl = (const float*)d_in[8];
    const float* W1 = (const float*)d_in[9];
    const float* b1 = (const float*)d_in[10];
    const float* W2 = (const float*)d_in[11];
    const float* b2 = (const float*)d_in[12];

    float* ws = (float*)d_ws;
    float* u1 = ws;                    // 524288
    float* u2 = ws + 524288;           // 524288
    float* alpha0 = ws + 1048576;      // 512
    float* A1v = alpha0 + 512;
    float* A2v = alpha0 + 1024;
    float* c0 = alpha0 + 1536;
    float* c1 = alpha0 + 2048;
    float* c2 = alpha0 + 2560;
    float* WA = alpha0 + 3072;         // 4096
    float* WB = alpha0 + 3072 + 4096;  // 4096

    k_main<<<256, 256, 0, stream>>>(x, W0, b0, u1, u2, alpha0, A1v, A2v);
    k_small<<<64, 256, 0, stream>>>(wp, wpi, wr, wri, alpha0, A1v, A2v, WA, WB, c0, c1, c2);
    k_gout<<<256, 256, 0, stream>>>(x, W0, b0, u1, u2, WA, WB, Wl, bl, c0, c1, c2,
                                    W1, b1, W2, b2, (float*)d_out);
}